// Round 9
// baseline (4238.325 us; speedup 1.0000x reference)
//
#include <hip/hip_runtime.h>
#include <cstddef>

#define HID 64
#define TT 64
#define NFEAT 8
#define TOUTC 12
#define SPB 8           // 8 seqs per block; N-tile half-occupied, act folded across lanes
#define NBLK 1024
#define NTHR 256

typedef float f4 __attribute__((ext_vector_type(4)));
typedef _Float16 h8 __attribute__((ext_vector_type(8)));
typedef unsigned int u32;
typedef unsigned long long u64;

#define MFMA16 __builtin_amdgcn_mfma_f32_16x16x32_f16

__device__ __forceinline__ float sigm(float x)  { return 1.0f / (1.0f + __expf(-x)); }
__device__ __forceinline__ float tanh_(float x) { return 1.0f - 2.0f / (__expf(2.0f * x) + 1.0f); }

__device__ __forceinline__ void splitf16(const float* v, h8& hi, h8& lo) {
#pragma unroll
    for (int j = 0; j < 8; ++j) {
        _Float16 h = (_Float16)v[j];
        hi[j] = h;
        lo[j] = (_Float16)(v[j] - (float)h);
    }
}

// Barrier: drain LDS, raw barrier, allow everything EXCEPT DS to cross.
#define STEP_BAR() do {                                         \
    asm volatile("s_waitcnt lgkmcnt(0)" ::: "memory");          \
    __builtin_amdgcn_s_barrier();                               \
    __builtin_amdgcn_sched_barrier(0x7F);                       \
} while (0)

// LDS: zh [2][16][64] fp16 (4096 B, swizzle byte ^= (cs&7)<<4), hs f32[16][68].
// Only seq rows 0..7 are live; rows 8..15 stay zero (deterministic, unused cols).
// ws: fp16 [seq][t][HID]; dbuf across layers when ws_size allows, else in-place.
//
// MFMA 16x16x32 f16: M = gate rows (4 tiles i,f,g,o x wave's 16 hidden units),
// N = 16 cols (8 valid seqs), K = [x (KSX*32); h (2*32)].
// A frag: row=l&15, k=8*(l>>4)+j. B frag: col=l&15. C/D: col=l&15, row=4*(l>>4)+r.
// 2 chains/gate (w-hi, w-lo). Activation folded: lanes cs<8 process rows {0,1},
// lanes cs>=8 take rows {2,3} of seq cs-8 via shfl_xor(8) -> 2 cells/lane.
template<int KSX, bool FIRST, bool LAST>
__device__ __forceinline__ void run_layer(
    const float* __restrict__ Wih, const float* __restrict__ Whh,
    const float* __restrict__ bi,  const float* __restrict__ bh_,
    const float* __restrict__ Xj,
    const unsigned short* __restrict__ rbuf, unsigned short* __restrict__ wbuf,
    char* zh, float* hs, int tid, int seq0)
{
    constexpr int NKS = KSX + 2;
    const int lane = tid & 63;
    const int wv   = tid >> 6;
    const int cs   = lane & 15;
    const int rq   = lane >> 4;
    const int hb   = 16 * wv + 4 * rq;
    const int swz  = (cs & 7) << 4;
    const int seqL = cs & 7;              // owned sequence (both lane halves)
    const int h0   = (cs >> 3) & 1;       // 0: rows {0,1}; 1: rows {2,3}
    const int seq  = seq0 + seqL;

    f4 z4 = {0.f, 0.f, 0.f, 0.f};

    // ---- weight A-fragments (fp16 hi/lo) ----
    h8 Ah[4][NKS], Al[4][NKS];
#pragma unroll
    for (int a = 0; a < 4; ++a) {
        const int row = 64 * a + 16 * wv + cs;
#pragma unroll
        for (int ks = 0; ks < NKS; ++ks) {
            float v[8];
            if (ks < KSX) {
                if (FIRST) {
                    const float* p = Wih + (size_t)row * NFEAT;
#pragma unroll
                    for (int j = 0; j < 8; ++j) v[j] = (rq == 0) ? p[j] : 0.0f;
                } else {
                    const float* p = Wih + (size_t)row * HID + 32 * ks + 8 * rq;
#pragma unroll
                    for (int j = 0; j < 8; ++j) v[j] = p[j];
                }
            } else {
                const float* p = Whh + (size_t)row * HID + 32 * (ks - KSX) + 8 * rq;
#pragma unroll
                for (int j = 0; j < 8; ++j) v[j] = p[j];
            }
            splitf16(v, Ah[a][ks], Al[a][ks]);
        }
    }

    // ---- bias (C/D layout) — MFMA C-init ----
    f4 bias[4];
#pragma unroll
    for (int a = 0; a < 4; ++a)
        bias[a] = *(const f4*)(bi + 64 * a + hb) + *(const f4*)(bh_ + 64 * a + hb);

    // ---- zero both zh planes (4096 B = 1024 u32) ----
#pragma unroll
    for (int i = 0; i < 4; ++i)
        ((u32*)zh)[tid * 4 + i] = 0u;

    float c0[2] = {0.f, 0.f};

    __syncthreads();   // drains prev-layer ws stores (vmcnt) + zh zero visible

    // ---- x prefetch: depth 2, parity register sets ----
    h8 xE[KSX], xO[KSX];
    f4 fE[2], fO[2];

    auto PREF = [&](int t, h8 (&hx)[KSX], f4 (&fx)[2]) {
        if constexpr (FIRST) {
            if (rq == 0) {
                const float* pX = Xj + ((size_t)seq * TT + t) * NFEAT;
                fx[0] = *(const f4*)pX;
                fx[1] = *(const f4*)(pX + 4);
            } else {
                fx[0] = z4; fx[1] = z4;
            }
        } else {
            const unsigned short* pR = rbuf + ((size_t)seq * TT + t) * HID + 8 * rq;
#pragma unroll
            for (int ks = 0; ks < KSX; ++ks)
                hx[ks] = *(const h8*)(pR + 32 * ks);
        }
    };

    PREF(0, xE, fE);
    PREF(1, xO, fO);

    auto STEP = [&](int t, int p, h8 (&hx)[KSX], f4 (&fx)[2]) {
        // ---- x B-fragments, then refill parity regs for t+2 ----
        h8 bx[KSX];
        if constexpr (FIRST) {
#pragma unroll
            for (int j = 0; j < 4; ++j) {
                bx[0][j]     = (_Float16)fx[0][j];
                bx[0][4 + j] = (_Float16)fx[1][j];
            }
        } else {
#pragma unroll
            for (int ks = 0; ks < KSX; ++ks) bx[ks] = hx[ks];
        }
        if (t + 2 < TT) PREF(t + 2, hx, fx);

        // ---- h B-fragments from LDS (swizzled) ----
        h8 bhh[2];
#pragma unroll
        for (int kk = 0; kk < 2; ++kk) {
            const int ho = p * 2048 + ((cs * 128 + 64 * kk + 16 * rq) ^ swz);
            bhh[kk] = *(const h8*)(zh + ho);
        }

        // ---- MFMA cluster: 2 chains per gate, bias as C-init ----
        f4 c1[4], c2[4];
        __builtin_amdgcn_s_setprio(1);
#pragma unroll
        for (int a = 0; a < 4; ++a) {
            c1[a] = MFMA16(Ah[a][0], bx[0], bias[a], 0, 0, 0);
            c2[a] = MFMA16(Al[a][0], bx[0], z4,      0, 0, 0);
            if constexpr (KSX == 2) {
                c1[a] = MFMA16(Ah[a][1], bx[1], c1[a], 0, 0, 0);
                c2[a] = MFMA16(Al[a][1], bx[1], c2[a], 0, 0, 0);
            }
        }
#pragma unroll
        for (int a = 0; a < 4; ++a) {
            c1[a] = MFMA16(Ah[a][KSX + 0], bhh[0], c1[a], 0, 0, 0);
            c2[a] = MFMA16(Al[a][KSX + 0], bhh[0], c2[a], 0, 0, 0);
            c1[a] = MFMA16(Ah[a][KSX + 1], bhh[1], c1[a], 0, 0, 0);
            c2[a] = MFMA16(Al[a][KSX + 1], bhh[1], c2[a], 0, 0, 0);
        }
        __builtin_amdgcn_s_setprio(0);

        // ---- gate fold: lanes cs>=8 take rows {2,3} of partner seq ----
        float ga0[4], ga1[4];
#pragma unroll
        for (int a = 0; a < 4; ++a) {
            float g0 = c1[a][0] + c2[a][0];
            float g1 = c1[a][1] + c2[a][1];
            float g2 = c1[a][2] + c2[a][2];
            float g3 = c1[a][3] + c2[a][3];
            float x2 = __shfl_xor(g2, 8);
            float x3 = __shfl_xor(g3, 8);
            ga0[a] = h0 ? x2 : g0;
            ga1[a] = h0 ? x3 : g1;
        }

        // ---- activations: 2 cells per lane ----
        float hv0, hv1;
        {
            float ig = sigm(ga0[0]), fg = sigm(ga0[1]);
            float gg = tanh_(ga0[2]), og = sigm(ga0[3]);
            float cc = fg * c0[0] + ig * gg;
            c0[0] = cc;
            hv0 = og * tanh_(cc);
        }
        {
            float ig = sigm(ga1[0]), fg = sigm(ga1[1]);
            float gg = tanh_(ga1[2]), og = sigm(ga1[3]);
            float cc = fg * c0[1] + ig * gg;
            c0[1] = cc;
            hv1 = og * tanh_(cc);
        }

        // ---- pack 2 fp16; write LDS ping (u32) + ws (u32) ----
        u32 ph;
        {
            _Float16 a0 = (_Float16)hv0, a1 = (_Float16)hv1;
            ph = (u32)(*(const unsigned short*)&a0) |
                 ((u32)(*(const unsigned short*)&a1) << 16);
        }
        const int elem = hb + 2 * h0;           // hidden index of first element
        {
            const int wo = (1 ^ p) * 2048 + ((seqL * 128 + 2 * elem) ^ swz);
            *(u32*)(zh + wo) = ph;
        }
        if constexpr (!LAST) {
            *(u32*)(wbuf + ((size_t)seq * TT + t) * HID + elem) = ph;
        } else {
            if (t == TT - 1) {
                float o0 = __shfl_xor(hv0, 8);   // partner's rows
                float o1 = __shfl_xor(hv1, 8);
                if (!h0) {
                    f4 hvec = {hv0, hv1, o0, o1};
                    *(f4*)(hs + cs * 68 + hb) = hvec;
                }
            }
        }

        STEP_BAR();
    };

#pragma unroll 1
    for (int tb = 0; tb < TT; tb += 2) {
        STEP(tb,     0, xE, fE);
        STEP(tb + 1, 1, xO, fO);
    }
}

__global__ __launch_bounds__(NTHR, 4)
void lstm_mfma16(const float* __restrict__ Xj,
                 const float* __restrict__ Wih0, const float* __restrict__ Whh0,
                 const float* __restrict__ bih0, const float* __restrict__ bhh0,
                 const float* __restrict__ WihR, const float* __restrict__ WhhR,
                 const float* __restrict__ bihR, const float* __restrict__ bhhR,
                 const float* __restrict__ Wout, const float* __restrict__ bout,
                 float* __restrict__ out,
                 unsigned short* __restrict__ ws0, unsigned short* __restrict__ ws1)
{
    __shared__ char smraw[8448];
    char*  zh = smraw;                    // [2][16][64] fp16
    float* hs = (float*)(smraw + 4096);   // [16][68] f32 (rows 0..7 used)

    const int tid  = threadIdx.x;
    const int seq0 = blockIdx.x * SPB;

    run_layer<1, true,  false>(Wih0, Whh0, bih0, bhh0, Xj, ws0, ws0, zh, hs, tid, seq0);
    run_layer<2, false, false>(WihR + (size_t)0 * 256 * HID, WhhR + (size_t)0 * 256 * HID,
                               bihR + 0 * 256, bhhR + 0 * 256, nullptr, ws0, ws1, zh, hs, tid, seq0);
    run_layer<2, false, false>(WihR + (size_t)1 * 256 * HID, WhhR + (size_t)1 * 256 * HID,
                               bihR + 1 * 256, bhhR + 1 * 256, nullptr, ws1, ws0, zh, hs, tid, seq0);
    run_layer<2, false, false>(WihR + (size_t)2 * 256 * HID, WhhR + (size_t)2 * 256 * HID,
                               bihR + 2 * 256, bhhR + 2 * 256, nullptr, ws0, ws1, zh, hs, tid, seq0);
    run_layer<2, false, true >(WihR + (size_t)3 * 256 * HID, WhhR + (size_t)3 * 256 * HID,
                               bihR + 3 * 256, bhhR + 3 * 256, nullptr, ws1, ws0, zh, hs, tid, seq0);

    __syncthreads();
    // ---- output projection: 8 seqs x 12 outs = 96 items ----
    for (int it = tid; it < SPB * TOUTC; it += NTHR) {
        int s = it / TOUTC, o = it % TOUTC;
        float sum = bout[o];
#pragma unroll 8
        for (int j = 0; j < HID; ++j)
            sum = fmaf(Wout[o * HID + j], hs[s * 68 + j], sum);
        out[(size_t)(seq0 + s) * TOUTC + o] = sum;
    }
}

extern "C" void kernel_launch(void* const* d_in, const int* in_sizes, int n_in,
                              void* d_out, int out_size, void* d_ws, size_t ws_size,
                              hipStream_t stream)
{
    const float* Xj   = (const float*)d_in[1];
    const float* Wih0 = (const float*)d_in[3];
    const float* Whh0 = (const float*)d_in[4];
    const float* bih0 = (const float*)d_in[5];
    const float* bhh0 = (const float*)d_in[6];
    const float* WihR = (const float*)d_in[7];
    const float* WhhR = (const float*)d_in[8];
    const float* bihR = (const float*)d_in[9];
    const float* bhhR = (const float*)d_in[10];
    const float* Wout = (const float*)d_in[11];
    const float* bout = (const float*)d_in[12];
    float* out = (float*)d_out;

    unsigned short* ws = (unsigned short*)d_ws;
    const size_t half_elems = (size_t)8192 * TT * HID;   // 33.5M shorts = 67 MB
    const bool dbuf = ws_size >= 2 * half_elems * sizeof(unsigned short);
    unsigned short* ws0 = ws;
    unsigned short* ws1 = dbuf ? (ws + half_elems) : ws;   // in-place fallback (R6-proven)

    lstm_mfma16<<<NBLK, NTHR, 0, stream>>>(Xj, Wih0, Whh0, bih0, bhh0,
                                           WihR, WhhR, bihR, bhhR,
                                           Wout, bout, out, ws0, ws1);
}

// Round 10
// 744.546 us; speedup vs baseline: 5.6925x; 5.6925x over previous
//
#include <hip/hip_runtime.h>
#include <cstddef>

#define HID 64
#define TT 64
#define NFEAT 8
#define TOUTC 12
#define SPB 8           // 8 seqs/block; N-tile cols duplicated, act folded across lane halves
#define NBLK 1024
#define NTHR 256

typedef float f4 __attribute__((ext_vector_type(4)));
typedef _Float16 h8 __attribute__((ext_vector_type(8)));
typedef unsigned int u32;
typedef unsigned long long u64;

#define MFMA16 __builtin_amdgcn_mfma_f32_16x16x32_f16

__device__ __forceinline__ float sigm(float x)  { return 1.0f / (1.0f + __expf(-x)); }
__device__ __forceinline__ float tanh_(float x) { return 1.0f - 2.0f / (__expf(2.0f * x) + 1.0f); }

// Barrier: drain LDS, raw barrier, allow everything EXCEPT DS to cross.
#define STEP_BAR() do {                                         \
    asm volatile("s_waitcnt lgkmcnt(0)" ::: "memory");          \
    __builtin_amdgcn_s_barrier();                               \
    __builtin_amdgcn_sched_barrier(0x7F);                       \
} while (0)

// LDS: zh [2][16][64] fp16 (4096 B, swizzle byte ^= (cs&7)<<4), hs f32[16][68].
// Seq rows 8..15 of zh mirror 0..7 (duplicated cols; deterministic).
// ws: fp16 [seq][t][HID]; dbuf across layers when ws_size allows, else in-place.
//
// MFMA 16x16x32 f16, SINGLE chain (W as fp16-RN; x,h fp16):
//   gate = bias (C-init) + Whi*[x;h].
// A frag: row=l&15, k=8*(l>>4)+j. B frag: col=l&15. C/D: col=l&15, row=4*(l>>4)+r.
// Activation folded: lanes cs<8 process rows {0,1}; lanes cs>=8 take rows {2,3}
// of seq cs-8 via shfl_xor(8) -> 2 cells/lane.
template<int KSX, bool FIRST, bool LAST>
__device__ __forceinline__ void run_layer(
    const float* __restrict__ Wih, const float* __restrict__ Whh,
    const float* __restrict__ bi,  const float* __restrict__ bh_,
    const float* __restrict__ Xj,
    const unsigned short* __restrict__ rbuf, unsigned short* __restrict__ wbuf,
    char* zh, float* hs, int tid, int seq0)
{
    constexpr int NKS = KSX + 2;
    const int lane = tid & 63;
    const int wv   = tid >> 6;
    const int cs   = lane & 15;
    const int rq   = lane >> 4;
    const int hb   = 16 * wv + 4 * rq;
    const int swz  = (cs & 7) << 4;
    const int seqL = cs & 7;
    const int h0   = (cs >> 3) & 1;
    const int seq  = seq0 + seqL;

    f4 z4 = {0.f, 0.f, 0.f, 0.f};

    // ---- weight A-fragments: single fp16 (RN) ----
    h8 Ah[4][NKS];
#pragma unroll
    for (int a = 0; a < 4; ++a) {
        const int row = 64 * a + 16 * wv + cs;
#pragma unroll
        for (int ks = 0; ks < NKS; ++ks) {
            float v[8];
            if (ks < KSX) {
                if (FIRST) {
                    const float* p = Wih + (size_t)row * NFEAT;
#pragma unroll
                    for (int j = 0; j < 8; ++j) v[j] = (rq == 0) ? p[j] : 0.0f;
                } else {
                    const float* p = Wih + (size_t)row * HID + 32 * ks + 8 * rq;
#pragma unroll
                    for (int j = 0; j < 8; ++j) v[j] = p[j];
                }
            } else {
                const float* p = Whh + (size_t)row * HID + 32 * (ks - KSX) + 8 * rq;
#pragma unroll
                for (int j = 0; j < 8; ++j) v[j] = p[j];
            }
#pragma unroll
            for (int j = 0; j < 8; ++j) Ah[a][ks][j] = (_Float16)v[j];
        }
    }

    // ---- bias (C/D layout) — MFMA C-init ----
    f4 bias[4];
#pragma unroll
    for (int a = 0; a < 4; ++a)
        bias[a] = *(const f4*)(bi + 64 * a + hb) + *(const f4*)(bh_ + 64 * a + hb);

    // ---- zero both zh planes (4096 B = 1024 u32) ----
#pragma unroll
    for (int i = 0; i < 4; ++i)
        ((u32*)zh)[tid * 4 + i] = 0u;

    float c0[2] = {0.f, 0.f};

    // ---- x prefetch: depth 1, single register set ----
    h8 xP[KSX];
    f4 fP[2];

    auto PREF = [&](int t) {
        if constexpr (FIRST) {
            if (rq == 0) {
                const float* pX = Xj + ((size_t)seq * TT + t) * NFEAT;
                fP[0] = *(const f4*)pX;
                fP[1] = *(const f4*)(pX + 4);
            } else {
                fP[0] = z4; fP[1] = z4;
            }
        } else {
            const unsigned short* pR = rbuf + ((size_t)seq * TT + t) * HID + 8 * rq;
#pragma unroll
            for (int ks = 0; ks < KSX; ++ks)
                xP[ks] = *(const h8*)(pR + 32 * ks);
        }
    };

    PREF(0);
    __syncthreads();   // drains vmcnt (PREF(0) + prev-layer ws stores) + zh zero visible

#pragma unroll 1
    for (int t = 0; t < TT; ++t) {
        const int p = t & 1;

        // ---- consume prefetch into bx, then refill for t+1 ----
        h8 bx[KSX];
        if constexpr (FIRST) {
#pragma unroll
            for (int j = 0; j < 4; ++j) {
                bx[0][j]     = (_Float16)fP[0][j];
                bx[0][4 + j] = (_Float16)fP[1][j];
            }
        } else {
#pragma unroll
            for (int ks = 0; ks < KSX; ++ks) bx[ks] = xP[ks];
        }
        if (t + 1 < TT) PREF(t + 1);

        // ---- h B-fragments from LDS (swizzled) ----
        h8 bhh[2];
#pragma unroll
        for (int kk = 0; kk < 2; ++kk) {
            const int ho = p * 2048 + ((cs * 128 + 64 * kk + 16 * rq) ^ swz);
            bhh[kk] = *(const h8*)(zh + ho);
        }

        // ---- MFMA cluster: single chain per gate, bias as C-init ----
        f4 c1[4];
        __builtin_amdgcn_s_setprio(1);
#pragma unroll
        for (int a = 0; a < 4; ++a) {
            c1[a] = MFMA16(Ah[a][0], bx[0], bias[a], 0, 0, 0);
            if constexpr (KSX == 2)
                c1[a] = MFMA16(Ah[a][1], bx[1], c1[a], 0, 0, 0);
        }
#pragma unroll
        for (int a = 0; a < 4; ++a) {
            c1[a] = MFMA16(Ah[a][KSX + 0], bhh[0], c1[a], 0, 0, 0);
            c1[a] = MFMA16(Ah[a][KSX + 1], bhh[1], c1[a], 0, 0, 0);
        }
        __builtin_amdgcn_s_setprio(0);

        // ---- gate fold: lanes cs>=8 take rows {2,3} of partner seq ----
        float ga0[4], ga1[4];
#pragma unroll
        for (int a = 0; a < 4; ++a) {
            float x2 = __shfl_xor(c1[a][2], 8);
            float x3 = __shfl_xor(c1[a][3], 8);
            ga0[a] = h0 ? x2 : c1[a][0];
            ga1[a] = h0 ? x3 : c1[a][1];
        }

        // ---- activations: 2 cells per lane ----
        float hv0, hv1;
        {
            float ig = sigm(ga0[0]), fg = sigm(ga0[1]);
            float gg = tanh_(ga0[2]), og = sigm(ga0[3]);
            float cc = fg * c0[0] + ig * gg;
            c0[0] = cc;
            hv0 = og * tanh_(cc);
        }
        {
            float ig = sigm(ga1[0]), fg = sigm(ga1[1]);
            float gg = tanh_(ga1[2]), og = sigm(ga1[3]);
            float cc = fg * c0[1] + ig * gg;
            c0[1] = cc;
            hv1 = og * tanh_(cc);
        }

        // ---- pack 2 fp16; write LDS ping (u32, both col-copies) + ws (u32) ----
        u32 ph;
        {
            _Float16 a0 = (_Float16)hv0, a1 = (_Float16)hv1;
            ph = (u32)(*(const unsigned short*)&a0) |
                 ((u32)(*(const unsigned short*)&a1) << 16);
        }
        const int elem = hb + 2 * h0;
        {
            // write own seq row and its duplicate row (seqL+8) so cols 8..15 stay valid
            const int base = (1 ^ p) * 2048;
            const int wo0 = base + ((seqL * 128 + 2 * elem) ^ swz);
            const int wo1 = base + (((seqL + 8) * 128 + 2 * elem) ^ swz);
            *(u32*)(zh + wo0) = ph;
            *(u32*)(zh + wo1) = ph;
        }
        if constexpr (!LAST) {
            *(u32*)(wbuf + ((size_t)seq * TT + t) * HID + elem) = ph;
        } else {
            if (t == TT - 1) {
                float o0 = __shfl_xor(hv0, 8);
                float o1 = __shfl_xor(hv1, 8);
                if (!h0) {
                    f4 hvec = {hv0, hv1, o0, o1};
                    *(f4*)(hs + cs * 68 + hb) = hvec;
                }
            }
        }

        STEP_BAR();
    }
}

__global__ __launch_bounds__(NTHR, 4)
void lstm_mfma16(const float* __restrict__ Xj,
                 const float* __restrict__ Wih0, const float* __restrict__ Whh0,
                 const float* __restrict__ bih0, const float* __restrict__ bhh0,
                 const float* __restrict__ WihR, const float* __restrict__ WhhR,
                 const float* __restrict__ bihR, const float* __restrict__ bhhR,
                 const float* __restrict__ Wout, const float* __restrict__ bout,
                 float* __restrict__ out,
                 unsigned short* __restrict__ ws0, unsigned short* __restrict__ ws1)
{
    __shared__ char smraw[8448];
    char*  zh = smraw;                    // [2][16][64] fp16
    float* hs = (float*)(smraw + 4096);   // [16][68] f32 (rows 0..7 used)

    const int tid  = threadIdx.x;
    const int seq0 = blockIdx.x * SPB;

    run_layer<1, true,  false>(Wih0, Whh0, bih0, bhh0, Xj, ws0, ws0, zh, hs, tid, seq0);
    run_layer<2, false, false>(WihR + (size_t)0 * 256 * HID, WhhR + (size_t)0 * 256 * HID,
                               bihR + 0 * 256, bhhR + 0 * 256, nullptr, ws0, ws1, zh, hs, tid, seq0);
    run_layer<2, false, false>(WihR + (size_t)1 * 256 * HID, WhhR + (size_t)1 * 256 * HID,
                               bihR + 1 * 256, bhhR + 1 * 256, nullptr, ws1, ws0, zh, hs, tid, seq0);
    run_layer<2, false, false>(WihR + (size_t)2 * 256 * HID, WhhR + (size_t)2 * 256 * HID,
                               bihR + 2 * 256, bhhR + 2 * 256, nullptr, ws0, ws1, zh, hs, tid, seq0);
    run_layer<2, false, true >(WihR + (size_t)3 * 256 * HID, WhhR + (size_t)3 * 256 * HID,
                               bihR + 3 * 256, bhhR + 3 * 256, nullptr, ws1, ws0, zh, hs, tid, seq0);

    __syncthreads();
    // ---- output projection: 8 seqs x 12 outs = 96 items ----
    for (int it = tid; it < SPB * TOUTC; it += NTHR) {
        int s = it / TOUTC, o = it % TOUTC;
        float sum = bout[o];
#pragma unroll 8
        for (int j = 0; j < HID; ++j)
            sum = fmaf(Wout[o * HID + j], hs[s * 68 + j], sum);
        out[(size_t)(seq0 + s) * TOUTC + o] = sum;
    }
}

extern "C" void kernel_launch(void* const* d_in, const int* in_sizes, int n_in,
                              void* d_out, int out_size, void* d_ws, size_t ws_size,
                              hipStream_t stream)
{
    const float* Xj   = (const float*)d_in[1];
    const float* Wih0 = (const float*)d_in[3];
    const float* Whh0 = (const float*)d_in[4];
    const float* bih0 = (const float*)d_in[5];
    const float* bhh0 = (const float*)d_in[6];
    const float* WihR = (const float*)d_in[7];
    const float* WhhR = (const float*)d_in[8];
    const float* bihR = (const float*)d_in[9];
    const float* bhhR = (const float*)d_in[10];
    const float* Wout = (const float*)d_in[11];
    const float* bout = (const float*)d_in[12];
    float* out = (float*)d_out;

    unsigned short* ws = (unsigned short*)d_ws;
    const size_t half_elems = (size_t)8192 * TT * HID;   // 33.5M shorts = 67 MB
    const bool dbuf = ws_size >= 2 * half_elems * sizeof(unsigned short);
    unsigned short* ws0 = ws;
    unsigned short* ws1 = dbuf ? (ws + half_elems) : ws;   // in-place fallback (R6-proven)

    lstm_mfma16<<<NBLK, NTHR, 0, stream>>>(Xj, Wih0, Whh0, bih0, bhh0,
                                           WihR, WhhR, bihR, bhhR,
                                           Wout, bout, out, ws0, ws1);
}